// Round 7
// baseline (390.946 us; speedup 1.0000x reference)
//
#include <hip/hip_runtime.h>
#include <math.h>

#define N_NODES 50000
#define IN_DIM 256
#define HEADS 4
#define CDIM 64
#define HC 256        // HEADS*CDIM
#define HOPS 3
#define EDGES 400000
#define NEG_SLOPE 0.2f
#define SEG (EDGES + N_NODES)            // hop0 flat range incl self-loops
#define TOT_E (3 * EDGES + N_NODES)      // flat edge count across hops
#define CAP 32                           // bucket = exactly one 128B line; P(deg>32) ~ 1e-6

// prep kernel block ranges
#define NB_GATE  ((N_NODES + 3) / 4)             // 12500
#define NB_PACKW ((IN_DIM * 2 * HC) / 256)       // 512
#define NB_SCAT  ((TOT_E + 255) / 256)           // 4883
// gemm grid (v1 shape, measured-best)
#define GEMM_BX  ((N_NODES + 127) / 128)         // 391

typedef unsigned short ushort;
using short8  = __attribute__((ext_vector_type(8))) short;
using floatx4 = __attribute__((ext_vector_type(4))) float;
using f32x2   = __attribute__((ext_vector_type(2))) float;

// flat layout: hop0 [0, E+N) incl self-loops ; hop1 [SEG, SEG+E) ; hop2 [...]
__device__ __forceinline__ void decode_flat(int f, int& k, int& e)
{
    if (f < SEG)              { k = 0; e = f; }
    else if (f < SEG + EDGES) { k = 1; e = f - SEG; }
    else                      { k = 2; e = f - SEG - EDGES; }
}

__device__ __forceinline__ ushort f2bf(float f)
{
    unsigned u = __float_as_uint(f);
    unsigned r = u + 0x7fffu + ((u >> 16) & 1u);   // RNE
    return (ushort)(r >> 16);
}

// unpack 2 bf16 (packed in a uint) -> f32x2 {lo, hi}
__device__ __forceinline__ f32x2 bf2x(unsigned u)
{
    f32x2 r;
    r.x = __uint_as_float(u << 16);
    r.y = __uint_as_float(u & 0xffff0000u);
    return r;
}

// leaky-relu slope 0.2: max(v, 0.2v)  -> v_pk_mul_f32 + v_pk_max_f32
__device__ __forceinline__ f32x2 lrelu2(f32x2 v)
{
    return __builtin_elementwise_max(v, 0.2f * v);
}

// ---------------------------------------------------------------------------
// prep: fused [gate+pack_x | pack_w | direct bucket scatter] by blockIdx range.
// (structure unchanged; CAP=32 -> one cache line per bucket)
// ---------------------------------------------------------------------------
__global__ __launch_bounds__(256) void prep(
    const float* __restrict__ X, const float* __restrict__ Wg,
    const float* __restrict__ bg, float* __restrict__ gw,
    ushort* __restrict__ Xb,
    const float* __restrict__ Wl, const float* __restrict__ Wr,
    ushort* __restrict__ WT,
    const int* __restrict__ ei0, const int* __restrict__ ei1,
    const int* __restrict__ ei2, int* __restrict__ cnt,
    int* __restrict__ bucket)
{
    const int blk = blockIdx.x;
    const int tid = threadIdx.x;

    if (blk < NB_GATE) {
        // ---- gate + bf16 pack of x: one wave per node ----
        const int node = (blk * 256 + tid) >> 6;
        const int lane = tid & 63;
        if (node >= N_NODES) return;

        float4 xv = ((const float4*)(X + (size_t)node * IN_DIM))[lane];

        union { ushort s[4]; uint2 u; } o;
        o.s[0] = f2bf(xv.x); o.s[1] = f2bf(xv.y);
        o.s[2] = f2bf(xv.z); o.s[3] = f2bf(xv.w);
        ((uint2*)(Xb + (size_t)node * IN_DIM))[lane] = o.u;

        float a0 = 0.f, a1 = 0.f, a2 = 0.f;
        const int i0 = lane * 4;
        a0 += xv.x * Wg[(i0 + 0) * HOPS + 0]; a1 += xv.x * Wg[(i0 + 0) * HOPS + 1]; a2 += xv.x * Wg[(i0 + 0) * HOPS + 2];
        a0 += xv.y * Wg[(i0 + 1) * HOPS + 0]; a1 += xv.y * Wg[(i0 + 1) * HOPS + 1]; a2 += xv.y * Wg[(i0 + 1) * HOPS + 2];
        a0 += xv.z * Wg[(i0 + 2) * HOPS + 0]; a1 += xv.z * Wg[(i0 + 2) * HOPS + 1]; a2 += xv.z * Wg[(i0 + 2) * HOPS + 2];
        a0 += xv.w * Wg[(i0 + 3) * HOPS + 0]; a1 += xv.w * Wg[(i0 + 3) * HOPS + 1]; a2 += xv.w * Wg[(i0 + 3) * HOPS + 2];

        #pragma unroll
        for (int off = 32; off >= 1; off >>= 1) {
            a0 += __shfl_xor(a0, off);
            a1 += __shfl_xor(a1, off);
            a2 += __shfl_xor(a2, off);
        }
        if (lane == 0) {
            float l0 = a0 + bg[0], l1 = a1 + bg[1], l2 = a2 + bg[2];
            float m = fmaxf(l0, fmaxf(l1, l2));
            float e0 = expf(l0 - m), e1 = expf(l1 - m), e2 = expf(l2 - m);
            float inv = 1.f / (e0 + e1 + e2);
            gw[node * HOPS + 0] = e0 * inv;
            gw[node * HOPS + 1] = e1 * inv;
            gw[node * HOPS + 2] = e2 * inv;
        }
    } else if (blk < NB_GATE + NB_PACKW) {
        // ---- pack W: WT[n][k]; coalesced writes, gather reads (W L2-resident)
        int id = (blk - NB_GATE) * 256 + tid;
        int n = id >> 8;            // 0..511
        int k = id & 255;           // 0..255
        float v = (n < HC) ? Wl[k * HC + n] : Wr[k * HC + (n - HC)];
        WT[(size_t)n * IN_DIM + k] = f2bf(v);
    } else {
        // ---- direct bucket scatter ----
        int f = (blk - NB_GATE - NB_PACKW) * 256 + tid;
        if (f >= TOT_E) return;
        int k, e; decode_flat(f, k, e);
        int s, d;
        if (k == 0 && e >= EDGES) { s = d = e - EDGES; }
        else {
            const int* ei = (k == 0) ? ei0 : (k == 1) ? ei1 : ei2;
            s = ei[e]; d = ei[EDGES + e];
        }
        int pos = atomicAdd(&cnt[k * N_NODES + d], 1);
        if (pos < CAP)
            bucket[((size_t)k * N_NODES + d) * CAP + pos] = s;
    }
}

// ---------------------------------------------------------------------------
// gemm v3: v1 shape (128x128 tile, blockIdx.y=4) with TK=64 — halves the
// barrier count (8 K-iters -> 4), 32 MFMAs/wave between barriers (was 16).
// Fragments loaded per k-slice inside the iter to keep VGPR near v1 levels.
// LDS 2 x 128x72x2B = 36.9 KB -> 4 blocks/CU.
// ---------------------------------------------------------------------------
#define TM 128
#define TN 128
#define TK 64
#define LDP 72

__global__ __launch_bounds__(256) void gemm_mfma(
    const ushort* __restrict__ Xb, const ushort* __restrict__ WT,
    const float* __restrict__ b_l, const float* __restrict__ b_r,
    ushort* __restrict__ xlb, ushort* __restrict__ xrb, int M)
{
    __shared__ ushort As[TM][LDP];
    __shared__ ushort Bs[TN][LDP];
    const int tid  = threadIdx.x;
    const int wave = tid >> 6, lane = tid & 63;
    const int row0 = blockIdx.x * TM;
    const int col0 = blockIdx.y * TN;
    const int wy = (wave >> 1) * 64, wx = (wave & 1) * 64;
    const int lrow = lane & 15, lk = (lane >> 4) * 8;

    floatx4 acc[4][4];
    #pragma unroll
    for (int i = 0; i < 4; i++)
        #pragma unroll
        for (int j = 0; j < 4; j++)
            acc[i][j] = (floatx4){0.f, 0.f, 0.f, 0.f};

    for (int k0 = 0; k0 < IN_DIM; k0 += TK) {
        // stage A,B 128x64 tiles: 1024 uint4-slots each, 4 per thread
        #pragma unroll
        for (int j = 0; j < 4; j++) {
            int id = tid + 256 * j;      // 0..1023
            int r  = id >> 3;            // 8 uint4-slots per 64-ch row
            int c  = (id & 7) * 8;
            int gr = row0 + r;
            uint4 v = make_uint4(0u, 0u, 0u, 0u);
            if (gr < M)
                v = *(const uint4*)(Xb + (size_t)gr * IN_DIM + k0 + c);
            *(uint4*)&As[r][c] = v;
        }
        #pragma unroll
        for (int j = 0; j < 4; j++) {
            int id = tid + 256 * j;
            int r  = id >> 3;
            int c  = (id & 7) * 8;
            *(uint4*)&Bs[r][c] =
                *(const uint4*)(WT + (size_t)(col0 + r) * IN_DIM + k0 + c);
        }
        __syncthreads();

        #pragma unroll
        for (int t = 0; t < 2; t++) {    // two k=32 slices per staged tile
            short8 af[4], bf[4];
            #pragma unroll
            for (int mi = 0; mi < 4; mi++)
                af[mi] = *(const short8*)&As[wy + mi * 16 + lrow][t * 32 + lk];
            #pragma unroll
            for (int ni = 0; ni < 4; ni++)
                bf[ni] = *(const short8*)&Bs[wx + ni * 16 + lrow][t * 32 + lk];

            #pragma unroll
            for (int mi = 0; mi < 4; mi++)
                #pragma unroll
                for (int ni = 0; ni < 4; ni++)
                    acc[mi][ni] = __builtin_amdgcn_mfma_f32_16x16x32_bf16(
                        bf[ni], af[mi], acc[mi][ni], 0, 0, 0);
        }
        __syncthreads();
    }

    const int csub = (lane >> 4) * 4;
    #pragma unroll
    for (int mi = 0; mi < 4; mi++) {
        int grow = row0 + wy + mi * 16 + lrow;
        if (grow < M) {
            #pragma unroll
            for (int ni = 0; ni < 4; ni++) {
                int gcol = col0 + wx + ni * 16 + csub;
                floatx4 v = acc[mi][ni];
                const bool left = (gcol < HC);
                const float4 b = left ? *(const float4*)(b_l + gcol)
                                      : *(const float4*)(b_r + gcol - HC);
                union { ushort s[4]; uint2 u; } o;
                o.s[0] = f2bf(v[0] + b.x);
                o.s[1] = f2bf(v[1] + b.y);
                o.s[2] = f2bf(v[2] + b.z);
                o.s[3] = f2bf(v[3] + b.w);
                ushort* dst = left ? (xlb + (size_t)grow * HC + gcol)
                                   : (xrb + (size_t)grow * HC + gcol - HC);
                *(uint2*)dst = o.u;
            }
        }
    }
}

// ---------------------------------------------------------------------------
// node_all v7 (REVERTED to measured-best: 141.5 µs, occ 80%, VALUBusy 67%):
// one 192-thread block (3 waves) per node; wave k = hop k; packed-f32 math;
// depth-1 prefetch (depth-2 measured neutral in r6).
// ---------------------------------------------------------------------------
__global__ __launch_bounds__(192) void node_all(
    const ushort* __restrict__ xlb, const ushort* __restrict__ xrb,
    const int* __restrict__ cnt, const int* __restrict__ bucket,
    const float* __restrict__ att, const float* __restrict__ gw,
    const float* __restrict__ bias, float* __restrict__ out)
{
    __shared__ float lds[HOPS][CDIM];
    const int n    = blockIdx.x;
    const int k    = threadIdx.x >> 6;   // hop
    const int lane = threadIdx.x & 63;
    const int half = lane >> 5;          // which edge of the pair
    const int sub  = lane & 31;          // channel group: ch = sub*8 .. sub*8+7
    const unsigned laneoff = (unsigned)sub * 8;

    const int deg = min(cnt[k * N_NODES + n], CAP);
    const int* bk = bucket + ((size_t)k * N_NODES + n) * CAP;

    // xr channels for this lane (bf16 -> f32x2 pairs)
    uint4 rq = *(const uint4*)(xrb + (size_t)n * HC + laneoff);
    f32x2 rr[4] = { bf2x(rq.x), bf2x(rq.y), bf2x(rq.z), bf2x(rq.w) };

    const float4 a0 = ((const float4*)(att + (size_t)k * HC))[sub * 2 + 0];
    const float4 a1 = ((const float4*)(att + (size_t)k * HC))[sub * 2 + 1];
    f32x2 w2[4] = { {a0.x, a0.y}, {a0.z, a0.w}, {a1.x, a1.y}, {a1.z, a1.w} };

    float denom = 0.f;
    f32x2 acc2[4] = { {0.f,0.f}, {0.f,0.f}, {0.f,0.f}, {0.f,0.f} };

    if (deg > 0) {
        const int degm1 = deg - 1;
        int myS = (lane < deg) ? bk[lane] : 0;
        const int npair = (deg + 1) >> 1;

        int s0 = __shfl(myS, min(half, degm1));
        uint4 q = *(const uint4*)(xlb + (unsigned)s0 * HC + laneoff);

        for (int j = 0; j < npair; j++) {
            int sn = __shfl(myS, min(2 * (j + 1) + half, degm1));
            uint4 qn = *(const uint4*)(xlb + (unsigned)sn * HC + laneoff);

            f32x2 f0 = bf2x(q.x), f1 = bf2x(q.y);
            f32x2 f2 = bf2x(q.z), f3 = bf2x(q.w);

            f32x2 pp = w2[0] * lrelu2(f0 + rr[0]);
            pp = __builtin_elementwise_fma(w2[1], lrelu2(f1 + rr[1]), pp);
            pp = __builtin_elementwise_fma(w2[2], lrelu2(f2 + rr[2]), pp);
            pp = __builtin_elementwise_fma(w2[3], lrelu2(f3 + rr[3]), pp);
            float p = pp.x + pp.y;

            // per-head reduce: head = 8 consecutive lanes (within half)
            p += __shfl_xor(p, 1);
            p += __shfl_xor(p, 2);
            p += __shfl_xor(p, 4);

            bool valid = (2 * j + half) < deg;
            float ex = valid ? __expf(p) : 0.f;
            denom += ex;
            f32x2 ex2 = { ex, ex };
            acc2[0] = __builtin_elementwise_fma(ex2, f0, acc2[0]);
            acc2[1] = __builtin_elementwise_fma(ex2, f1, acc2[1]);
            acc2[2] = __builtin_elementwise_fma(ex2, f2, acc2[2]);
            acc2[3] = __builtin_elementwise_fma(ex2, f3, acc2[3]);
            q = qn;
        }
    }

    // merge halves (xor-32): denom & acc are per-head after this.
    denom += __shfl_xor(denom, 32);
    const float inv = (denom > 0.f) ? 1.f / denom : 0.f;
    const float g   = gw[n * HOPS + k];
    const float* bb = bias + (size_t)k * CDIM + (size_t)(sub & 7) * 8;

    // per-head normalize FIRST (each lane still carries its own head),
    // THEN head mean across lanes {sub&7, +8, +16, +24} (xor-8, xor-16).
    #pragma unroll
    for (int i = 0; i < 4; i++) {
        acc2[i].x += __shfl_xor(acc2[i].x, 32);
        acc2[i].y += __shfl_xor(acc2[i].y, 32);
        acc2[i].x *= inv;
        acc2[i].y *= inv;
        acc2[i].x += __shfl_xor(acc2[i].x, 8);
        acc2[i].y += __shfl_xor(acc2[i].y, 8);
        acc2[i].x += __shfl_xor(acc2[i].x, 16);
        acc2[i].y += __shfl_xor(acc2[i].y, 16);
        if (lane < 8) {
            lds[k][lane * 8 + 2 * i]     = g * (acc2[i].x * 0.25f + bb[2 * i]);
            lds[k][lane * 8 + 2 * i + 1] = g * (acc2[i].y * 0.25f + bb[2 * i + 1]);
        }
    }
    __syncthreads();

    if (threadIdx.x < CDIM)
        out[(size_t)n * CDIM + threadIdx.x] =
            lds[0][threadIdx.x] + lds[1][threadIdx.x] + lds[2][threadIdx.x];
}

// ---------------------------------------------------------------------------
extern "C" void kernel_launch(void* const* d_in, const int* in_sizes, int n_in,
                              void* d_out, int out_size, void* d_ws, size_t ws_size,
                              hipStream_t stream)
{
    const float* x      = (const float*)d_in[0];
    const int*   ei0    = (const int*)d_in[1];
    const int*   ei1    = (const int*)d_in[2];
    const int*   ei2    = (const int*)d_in[3];
    const float* W_l    = (const float*)d_in[4];
    const float* b_l    = (const float*)d_in[5];
    const float* W_r    = (const float*)d_in[6];
    const float* b_r    = (const float*)d_in[7];
    const float* att    = (const float*)d_in[8];   // [3,4,64]
    const float* bias   = (const float*)d_in[9];   // [3,64]
    const float* W_gate = (const float*)d_in[10];  // [256,3]
    const float* b_gate = (const float*)d_in[11];  // [3]

    const size_t NHC = (size_t)N_NODES * HC;       // 12,800,000
    float* ws      = (float*)d_ws;
    float* gwbuf   = ws;                           // 150,000 floats
    int*   cnt     = (int*)(gwbuf + HOPS * N_NODES);         // 150,000 ints
    int*   bucket  = cnt + HOPS * N_NODES;         // 3*N*CAP = 4,800,000 ints (128B-aligned rows)
    ushort* xlb    = (ushort*)(bucket + (size_t)HOPS * N_NODES * CAP); // NHC bf16
    ushort* xrb    = xlb + NHC;                    // NHC bf16
    ushort* Xb     = xrb + NHC;                    // NHC bf16
    ushort* WT     = Xb + NHC;                     // 131,072 bf16

    hipMemsetAsync(cnt, 0, (size_t)HOPS * N_NODES * sizeof(int), stream);

    // fused gate+pack_x | pack_w | bucket scatter
    prep<<<NB_GATE + NB_PACKW + NB_SCAT, 256, 0, stream>>>(
        x, W_gate, b_gate, gwbuf, Xb, W_l, W_r, WT,
        ei0, ei1, ei2, cnt, bucket);

    // bf16 MFMA GEMM v3 (TK=64) -> xlb | xrb (both bf16)
    dim3 ggrid(GEMM_BX, 4);
    gemm_mfma<<<ggrid, 256, 0, stream>>>(Xb, WT, b_l, b_r, xlb, xrb, N_NODES);

    // fused logits + softmax + aggregate + head-mean + gate combine
    node_all<<<N_NODES, 192, 0, stream>>>(
        xlb, xrb, cnt, bucket, att, gwbuf, bias, (float*)d_out);
}

// Round 8
// 372.319 us; speedup vs baseline: 1.0500x; 1.0500x over previous
//
#include <hip/hip_runtime.h>
#include <math.h>

#define N_NODES 50000
#define IN_DIM 256
#define HEADS 4
#define CDIM 64
#define HC 256        // HEADS*CDIM
#define HOPS 3
#define EDGES 400000
#define NEG_SLOPE 0.2f
#define SEG (EDGES + N_NODES)            // hop0 flat range incl self-loops
#define TOT_E (3 * EDGES + N_NODES)      // flat edge count across hops
#define CAP 40                           // bucket capacity (r4-best); P(Poisson(8)+1 > 40) ~ 1e-16

// prep_a kernel block ranges (gate+packx | packw)
#define NB_GATE  ((N_NODES + 3) / 4)             // 12500
#define NB_PACKW ((IN_DIM * 2 * HC) / 256)       // 512
#define NB_SCAT  ((TOT_E + 255) / 256)           // 4883
// gemm v1 grid (measured-best), flattened 1D + scatter blocks appended
#define GEMM_BX   ((N_NODES + 127) / 128)        // 391
#define GEMM_BLKS (GEMM_BX * 4)                  // 1564
#define FUSED_BLKS (GEMM_BLKS + NB_SCAT)         // 6447

typedef unsigned short ushort;
using short8  = __attribute__((ext_vector_type(8))) short;
using floatx4 = __attribute__((ext_vector_type(4))) float;
using f32x2   = __attribute__((ext_vector_type(2))) float;

// flat layout: hop0 [0, E+N) incl self-loops ; hop1 [SEG, SEG+E) ; hop2 [...]
__device__ __forceinline__ void decode_flat(int f, int& k, int& e)
{
    if (f < SEG)              { k = 0; e = f; }
    else if (f < SEG + EDGES) { k = 1; e = f - SEG; }
    else                      { k = 2; e = f - SEG - EDGES; }
}

__device__ __forceinline__ ushort f2bf(float f)
{
    unsigned u = __float_as_uint(f);
    unsigned r = u + 0x7fffu + ((u >> 16) & 1u);   // RNE
    return (ushort)(r >> 16);
}

// unpack 2 bf16 (packed in a uint) -> f32x2 {lo, hi}
__device__ __forceinline__ f32x2 bf2x(unsigned u)
{
    f32x2 r;
    r.x = __uint_as_float(u << 16);
    r.y = __uint_as_float(u & 0xffff0000u);
    return r;
}

// leaky-relu slope 0.2: max(v, 0.2v)  -> v_pk_mul_f32 + v_pk_max_f32
// (VOP3P has no abs input modifier, so this 2-op form is packed-minimal)
__device__ __forceinline__ f32x2 lrelu2(f32x2 v)
{
    return __builtin_elementwise_max(v, 0.2f * v);
}

// ---------------------------------------------------------------------------
// prep_a: [gate+pack_x | pack_w] only — the edge scatter moved into the gemm
// kernel's grid so it overlaps the (independent) GEMM work.
// ---------------------------------------------------------------------------
__global__ __launch_bounds__(256) void prep_a(
    const float* __restrict__ X, const float* __restrict__ Wg,
    const float* __restrict__ bg, float* __restrict__ gw,
    ushort* __restrict__ Xb,
    const float* __restrict__ Wl, const float* __restrict__ Wr,
    ushort* __restrict__ WT)
{
    const int blk = blockIdx.x;
    const int tid = threadIdx.x;

    if (blk < NB_GATE) {
        // ---- gate + bf16 pack of x: one wave per node ----
        const int node = (blk * 256 + tid) >> 6;
        const int lane = tid & 63;
        if (node >= N_NODES) return;

        float4 xv = ((const float4*)(X + (size_t)node * IN_DIM))[lane];

        union { ushort s[4]; uint2 u; } o;
        o.s[0] = f2bf(xv.x); o.s[1] = f2bf(xv.y);
        o.s[2] = f2bf(xv.z); o.s[3] = f2bf(xv.w);
        ((uint2*)(Xb + (size_t)node * IN_DIM))[lane] = o.u;

        float a0 = 0.f, a1 = 0.f, a2 = 0.f;
        const int i0 = lane * 4;
        a0 += xv.x * Wg[(i0 + 0) * HOPS + 0]; a1 += xv.x * Wg[(i0 + 0) * HOPS + 1]; a2 += xv.x * Wg[(i0 + 0) * HOPS + 2];
        a0 += xv.y * Wg[(i0 + 1) * HOPS + 0]; a1 += xv.y * Wg[(i0 + 1) * HOPS + 1]; a2 += xv.y * Wg[(i0 + 1) * HOPS + 2];
        a0 += xv.z * Wg[(i0 + 2) * HOPS + 0]; a1 += xv.z * Wg[(i0 + 2) * HOPS + 1]; a2 += xv.z * Wg[(i0 + 2) * HOPS + 2];
        a0 += xv.w * Wg[(i0 + 3) * HOPS + 0]; a1 += xv.w * Wg[(i0 + 3) * HOPS + 1]; a2 += xv.w * Wg[(i0 + 3) * HOPS + 2];

        #pragma unroll
        for (int off = 32; off >= 1; off >>= 1) {
            a0 += __shfl_xor(a0, off);
            a1 += __shfl_xor(a1, off);
            a2 += __shfl_xor(a2, off);
        }
        if (lane == 0) {
            float l0 = a0 + bg[0], l1 = a1 + bg[1], l2 = a2 + bg[2];
            float m = fmaxf(l0, fmaxf(l1, l2));
            float e0 = expf(l0 - m), e1 = expf(l1 - m), e2 = expf(l2 - m);
            float inv = 1.f / (e0 + e1 + e2);
            gw[node * HOPS + 0] = e0 * inv;
            gw[node * HOPS + 1] = e1 * inv;
            gw[node * HOPS + 2] = e2 * inv;
        }
    } else {
        // ---- pack W: WT[n][k]; coalesced writes, gather reads (W L2-resident)
        int id = (blk - NB_GATE) * 256 + tid;
        int n = id >> 8;            // 0..511
        int k = id & 255;           // 0..255
        float v = (n < HC) ? Wl[k * HC + n] : Wr[k * HC + (n - HC)];
        WT[(size_t)n * IN_DIM + k] = f2bf(v);
    }
}

// ---------------------------------------------------------------------------
// gemm_scatter: gemm v1 (measured-best 128x128, TK=32) on blocks [0,1564) +
// the edge bucket scatter on blocks [1564, 6447). The scatter is independent
// of gemm's data (needs only ei*/cnt), memory/atomic-bound vs gemm's
// LDS/MFMA-bound -> runs in the gemm's shadow instead of serialized after.
// ---------------------------------------------------------------------------
#define TM 128
#define TN 128
#define TK 32
#define LDP 40

__global__ __launch_bounds__(256) void gemm_scatter(
    const ushort* __restrict__ Xb, const ushort* __restrict__ WT,
    const float* __restrict__ b_l, const float* __restrict__ b_r,
    ushort* __restrict__ xlb, ushort* __restrict__ xrb, int M,
    const int* __restrict__ ei0, const int* __restrict__ ei1,
    const int* __restrict__ ei2, int* __restrict__ cnt,
    int* __restrict__ bucket)
{
    __shared__ ushort As[TM][LDP];
    __shared__ ushort Bs[TN][LDP];
    const int blk = blockIdx.x;
    const int tid = threadIdx.x;

    if (blk >= GEMM_BLKS) {
        // ---- direct bucket scatter ----
        int f = (blk - GEMM_BLKS) * 256 + tid;
        if (f >= TOT_E) return;
        int k, e; decode_flat(f, k, e);
        int s, d;
        if (k == 0 && e >= EDGES) { s = d = e - EDGES; }
        else {
            const int* ei = (k == 0) ? ei0 : (k == 1) ? ei1 : ei2;
            s = ei[e]; d = ei[EDGES + e];
        }
        int pos = atomicAdd(&cnt[k * N_NODES + d], 1);
        if (pos < CAP)
            bucket[((size_t)k * N_NODES + d) * CAP + pos] = s;
        return;
    }

    // ---- gemm v1 (1D-decomposed: same order as the old (x=391, y=4) grid) ----
    const int bx   = blk % GEMM_BX;
    const int by   = blk / GEMM_BX;
    const int wave = tid >> 6, lane = tid & 63;
    const int row0 = bx * TM;
    const int col0 = by * TN;
    const int wy = (wave >> 1) * 64, wx = (wave & 1) * 64;
    const int lrow = lane & 15, lk = (lane >> 4) * 8;

    floatx4 acc[4][4];
    #pragma unroll
    for (int i = 0; i < 4; i++)
        #pragma unroll
        for (int j = 0; j < 4; j++)
            acc[i][j] = (floatx4){0.f, 0.f, 0.f, 0.f};

    for (int k0 = 0; k0 < IN_DIM; k0 += TK) {
        #pragma unroll
        for (int j = 0; j < 2; j++) {
            int id = tid + 256 * j;
            int r  = id >> 2;
            int c  = (id & 3) * 8;
            int gr = row0 + r;
            uint4 v = make_uint4(0u, 0u, 0u, 0u);
            if (gr < M)
                v = *(const uint4*)(Xb + (size_t)gr * IN_DIM + k0 + c);
            *(uint4*)&As[r][c] = v;
        }
        #pragma unroll
        for (int j = 0; j < 2; j++) {
            int id = tid + 256 * j;
            int r  = id >> 2;
            int c  = (id & 3) * 8;
            *(uint4*)&Bs[r][c] =
                *(const uint4*)(WT + (size_t)(col0 + r) * IN_DIM + k0 + c);
        }
        __syncthreads();

        short8 af[4], bf[4];
        #pragma unroll
        for (int mi = 0; mi < 4; mi++)
            af[mi] = *(const short8*)&As[wy + mi * 16 + lrow][lk];
        #pragma unroll
        for (int ni = 0; ni < 4; ni++)
            bf[ni] = *(const short8*)&Bs[wx + ni * 16 + lrow][lk];

        #pragma unroll
        for (int mi = 0; mi < 4; mi++)
            #pragma unroll
            for (int ni = 0; ni < 4; ni++)
                acc[mi][ni] = __builtin_amdgcn_mfma_f32_16x16x32_bf16(
                    bf[ni], af[mi], acc[mi][ni], 0, 0, 0);
        __syncthreads();
    }

    const int csub = (lane >> 4) * 4;
    #pragma unroll
    for (int mi = 0; mi < 4; mi++) {
        int grow = row0 + wy + mi * 16 + lrow;
        if (grow < M) {
            #pragma unroll
            for (int ni = 0; ni < 4; ni++) {
                int gcol = col0 + wx + ni * 16 + csub;
                floatx4 v = acc[mi][ni];
                const bool left = (gcol < HC);
                const float4 b = left ? *(const float4*)(b_l + gcol)
                                      : *(const float4*)(b_r + gcol - HC);
                union { ushort s[4]; uint2 u; } o;
                o.s[0] = f2bf(v[0] + b.x);
                o.s[1] = f2bf(v[1] + b.y);
                o.s[2] = f2bf(v[2] + b.z);
                o.s[3] = f2bf(v[3] + b.w);
                ushort* dst = left ? (xlb + (size_t)grow * HC + gcol)
                                   : (xrb + (size_t)grow * HC + gcol - HC);
                *(uint2*)dst = o.u;
            }
        }
    }
}

// ---------------------------------------------------------------------------
// node_all v7 (UNCHANGED — measured-best 141.5 µs, occ 80%, VALUBusy 67%):
// one 192-thread block (3 waves) per node; wave k = hop k; packed-f32 math;
// depth-1 prefetch (depth-2 measured neutral in r6).
// ---------------------------------------------------------------------------
__global__ __launch_bounds__(192) void node_all(
    const ushort* __restrict__ xlb, const ushort* __restrict__ xrb,
    const int* __restrict__ cnt, const int* __restrict__ bucket,
    const float* __restrict__ att, const float* __restrict__ gw,
    const float* __restrict__ bias, float* __restrict__ out)
{
    __shared__ float lds[HOPS][CDIM];
    const int n    = blockIdx.x;
    const int k    = threadIdx.x >> 6;   // hop
    const int lane = threadIdx.x & 63;
    const int half = lane >> 5;          // which edge of the pair
    const int sub  = lane & 31;          // channel group: ch = sub*8 .. sub*8+7
    const unsigned laneoff = (unsigned)sub * 8;

    const int deg = min(cnt[k * N_NODES + n], CAP);
    const int* bk = bucket + ((size_t)k * N_NODES + n) * CAP;

    // xr channels for this lane (bf16 -> f32x2 pairs)
    uint4 rq = *(const uint4*)(xrb + (size_t)n * HC + laneoff);
    f32x2 rr[4] = { bf2x(rq.x), bf2x(rq.y), bf2x(rq.z), bf2x(rq.w) };

    const float4 a0 = ((const float4*)(att + (size_t)k * HC))[sub * 2 + 0];
    const float4 a1 = ((const float4*)(att + (size_t)k * HC))[sub * 2 + 1];
    f32x2 w2[4] = { {a0.x, a0.y}, {a0.z, a0.w}, {a1.x, a1.y}, {a1.z, a1.w} };

    float denom = 0.f;
    f32x2 acc2[4] = { {0.f,0.f}, {0.f,0.f}, {0.f,0.f}, {0.f,0.f} };

    if (deg > 0) {
        const int degm1 = deg - 1;
        int myS = (lane < deg) ? bk[lane] : 0;
        const int npair = (deg + 1) >> 1;

        int s0 = __shfl(myS, min(half, degm1));
        uint4 q = *(const uint4*)(xlb + (unsigned)s0 * HC + laneoff);

        for (int j = 0; j < npair; j++) {
            int sn = __shfl(myS, min(2 * (j + 1) + half, degm1));
            uint4 qn = *(const uint4*)(xlb + (unsigned)sn * HC + laneoff);

            f32x2 f0 = bf2x(q.x), f1 = bf2x(q.y);
            f32x2 f2 = bf2x(q.z), f3 = bf2x(q.w);

            f32x2 pp = w2[0] * lrelu2(f0 + rr[0]);
            pp = __builtin_elementwise_fma(w2[1], lrelu2(f1 + rr[1]), pp);
            pp = __builtin_elementwise_fma(w2[2], lrelu2(f2 + rr[2]), pp);
            pp = __builtin_elementwise_fma(w2[3], lrelu2(f3 + rr[3]), pp);
            float p = pp.x + pp.y;

            // per-head reduce: head = 8 consecutive lanes (within half)
            p += __shfl_xor(p, 1);
            p += __shfl_xor(p, 2);
            p += __shfl_xor(p, 4);

            bool valid = (2 * j + half) < deg;
            float ex = valid ? __expf(p) : 0.f;
            denom += ex;
            f32x2 ex2 = { ex, ex };
            acc2[0] = __builtin_elementwise_fma(ex2, f0, acc2[0]);
            acc2[1] = __builtin_elementwise_fma(ex2, f1, acc2[1]);
            acc2[2] = __builtin_elementwise_fma(ex2, f2, acc2[2]);
            acc2[3] = __builtin_elementwise_fma(ex2, f3, acc2[3]);
            q = qn;
        }
    }

    // merge halves (xor-32): denom & acc are per-head after this.
    denom += __shfl_xor(denom, 32);
    const float inv = (denom > 0.f) ? 1.f / denom : 0.f;
    const float g   = gw[n * HOPS + k];
    const float* bb = bias + (size_t)k * CDIM + (size_t)(sub & 7) * 8;

    // per-head normalize FIRST (each lane still carries its own head),
    // THEN head mean across lanes {sub&7, +8, +16, +24} (xor-8, xor-16).
    #pragma unroll
    for (int i = 0; i < 4; i++) {
        acc2[i].x += __shfl_xor(acc2[i].x, 32);
        acc2[i].y += __shfl_xor(acc2[i].y, 32);
        acc2[i].x *= inv;
        acc2[i].y *= inv;
        acc2[i].x += __shfl_xor(acc2[i].x, 8);
        acc2[i].y += __shfl_xor(acc2[i].y, 8);
        acc2[i].x += __shfl_xor(acc2[i].x, 16);
        acc2[i].y += __shfl_xor(acc2[i].y, 16);
        if (lane < 8) {
            lds[k][lane * 8 + 2 * i]     = g * (acc2[i].x * 0.25f + bb[2 * i]);
            lds[k][lane * 8 + 2 * i + 1] = g * (acc2[i].y * 0.25f + bb[2 * i + 1]);
        }
    }
    __syncthreads();

    if (threadIdx.x < CDIM)
        out[(size_t)n * CDIM + threadIdx.x] =
            lds[0][threadIdx.x] + lds[1][threadIdx.x] + lds[2][threadIdx.x];
}

// ---------------------------------------------------------------------------
extern "C" void kernel_launch(void* const* d_in, const int* in_sizes, int n_in,
                              void* d_out, int out_size, void* d_ws, size_t ws_size,
                              hipStream_t stream)
{
    const float* x      = (const float*)d_in[0];
    const int*   ei0    = (const int*)d_in[1];
    const int*   ei1    = (const int*)d_in[2];
    const int*   ei2    = (const int*)d_in[3];
    const float* W_l    = (const float*)d_in[4];
    const float* b_l    = (const float*)d_in[5];
    const float* W_r    = (const float*)d_in[6];
    const float* b_r    = (const float*)d_in[7];
    const float* att    = (const float*)d_in[8];   // [3,4,64]
    const float* bias   = (const float*)d_in[9];   // [3,64]
    const float* W_gate = (const float*)d_in[10];  // [256,3]
    const float* b_gate = (const float*)d_in[11];  // [3]

    const size_t NHC = (size_t)N_NODES * HC;       // 12,800,000
    float* ws      = (float*)d_ws;
    float* gwbuf   = ws;                           // 150,000 floats
    int*   cnt     = (int*)(gwbuf + HOPS * N_NODES);         // 150,000 ints
    int*   bucket  = cnt + HOPS * N_NODES;         // 3*N*CAP = 6,000,000 ints
    ushort* xlb    = (ushort*)(bucket + (size_t)HOPS * N_NODES * CAP); // NHC bf16
    ushort* xrb    = xlb + NHC;                    // NHC bf16
    ushort* Xb     = xrb + NHC;                    // NHC bf16
    ushort* WT     = Xb + NHC;                     // 131,072 bf16

    hipMemsetAsync(cnt, 0, (size_t)HOPS * N_NODES * sizeof(int), stream);

    // gate + pack_x | pack_w
    prep_a<<<NB_GATE + NB_PACKW, 256, 0, stream>>>(
        x, W_gate, b_gate, gwbuf, Xb, W_l, W_r, WT);

    // gemm v1 + concurrent edge scatter (independent work, complementary pipes)
    gemm_scatter<<<FUSED_BLKS, 256, 0, stream>>>(
        Xb, WT, b_l, b_r, xlb, xrb, N_NODES,
        ei0, ei1, ei2, cnt, bucket);

    // fused logits + softmax + aggregate + head-mean + gate combine
    node_all<<<N_NODES, 192, 0, stream>>>(
        xlb, xrb, cnt, bucket, att, gwbuf, bias, (float*)d_out);
}

// Round 9
// 368.585 us; speedup vs baseline: 1.0607x; 1.0101x over previous
//
#include <hip/hip_runtime.h>
#include <math.h>

#define N_NODES 50000
#define IN_DIM 256
#define HEADS 4
#define CDIM 64
#define HC 256        // HEADS*CDIM
#define HOPS 3
#define EDGES 400000
#define NEG_SLOPE 0.2f
#define SEG (EDGES + N_NODES)            // hop0 flat range incl self-loops
#define TOT_E (3 * EDGES + N_NODES)      // flat edge count across hops
#define CAP 40                           // bucket capacity; P(Poisson(8)+1 > 40) ~ 1e-16
#define LOG2E 1.44269504f

// prep_a kernel block ranges (gate+packx | packw | zero-cnt)
#define NB_GATE  ((N_NODES + 3) / 4)             // 12500
#define NB_PACKW ((IN_DIM * 2 * HC) / 256)       // 512
#define NB_ZERO  ((HOPS * N_NODES + 255) / 256)  // 587
#define NB_SCAT  ((TOT_E + 255) / 256)           // 4883
// gemm v1 shape; XCD-aware 1D order: 32-block groups = 8 XCD x 4 col-blocks,
// so one XCD sees all 4 by of a given bx consecutively -> A-tile L2 reuse.
#define GEMM_BX    ((N_NODES + 127) / 128)       // 391
#define GEMM_GRP   ((GEMM_BX + 7) / 8)           // 49
#define GEMM_BLKS  (GEMM_GRP * 32)               // 1568 (4 idle tail blocks)
#define FUSED_BLKS (GEMM_BLKS + NB_SCAT)         // 6451

typedef unsigned short ushort;
using short8  = __attribute__((ext_vector_type(8))) short;
using floatx4 = __attribute__((ext_vector_type(4))) float;
using f32x2   = __attribute__((ext_vector_type(2))) float;

// flat layout: hop0 [0, E+N) incl self-loops ; hop1 [SEG, SEG+E) ; hop2 [...]
__device__ __forceinline__ void decode_flat(int f, int& k, int& e)
{
    if (f < SEG)              { k = 0; e = f; }
    else if (f < SEG + EDGES) { k = 1; e = f - SEG; }
    else                      { k = 2; e = f - SEG - EDGES; }
}

__device__ __forceinline__ ushort f2bf(float f)
{
    unsigned u = __float_as_uint(f);
    unsigned r = u + 0x7fffu + ((u >> 16) & 1u);   // RNE
    return (ushort)(r >> 16);
}

// unpack 2 bf16 (packed in a uint) -> f32x2 {lo, hi}
__device__ __forceinline__ f32x2 bf2x(unsigned u)
{
    f32x2 r;
    r.x = __uint_as_float(u << 16);
    r.y = __uint_as_float(u & 0xffff0000u);
    return r;
}

// leaky-relu slope 0.2: max(v, 0.2v)  -> v_pk_mul_f32 + v_pk_max_f32
// (VOP3P has no abs input modifier, so this 2-op form is packed-minimal)
__device__ __forceinline__ f32x2 lrelu2(f32x2 v)
{
    return __builtin_elementwise_max(v, 0.2f * v);
}

// ---------------------------------------------------------------------------
// prep_a: [gate+pack_x | pack_w | zero-cnt]. The cnt memset is folded in as a
// block range (saves one launch); the edge scatter lives in gemm_scatter.
// ---------------------------------------------------------------------------
__global__ __launch_bounds__(256) void prep_a(
    const float* __restrict__ X, const float* __restrict__ Wg,
    const float* __restrict__ bg, float* __restrict__ gw,
    ushort* __restrict__ Xb,
    const float* __restrict__ Wl, const float* __restrict__ Wr,
    ushort* __restrict__ WT, int* __restrict__ cnt)
{
    const int blk = blockIdx.x;
    const int tid = threadIdx.x;

    if (blk < NB_GATE) {
        // ---- gate + bf16 pack of x: one wave per node ----
        const int node = (blk * 256 + tid) >> 6;
        const int lane = tid & 63;
        if (node >= N_NODES) return;

        float4 xv = ((const float4*)(X + (size_t)node * IN_DIM))[lane];

        union { ushort s[4]; uint2 u; } o;
        o.s[0] = f2bf(xv.x); o.s[1] = f2bf(xv.y);
        o.s[2] = f2bf(xv.z); o.s[3] = f2bf(xv.w);
        ((uint2*)(Xb + (size_t)node * IN_DIM))[lane] = o.u;

        float a0 = 0.f, a1 = 0.f, a2 = 0.f;
        const int i0 = lane * 4;
        a0 += xv.x * Wg[(i0 + 0) * HOPS + 0]; a1 += xv.x * Wg[(i0 + 0) * HOPS + 1]; a2 += xv.x * Wg[(i0 + 0) * HOPS + 2];
        a0 += xv.y * Wg[(i0 + 1) * HOPS + 0]; a1 += xv.y * Wg[(i0 + 1) * HOPS + 1]; a2 += xv.y * Wg[(i0 + 1) * HOPS + 2];
        a0 += xv.z * Wg[(i0 + 2) * HOPS + 0]; a1 += xv.z * Wg[(i0 + 2) * HOPS + 1]; a2 += xv.z * Wg[(i0 + 2) * HOPS + 2];
        a0 += xv.w * Wg[(i0 + 3) * HOPS + 0]; a1 += xv.w * Wg[(i0 + 3) * HOPS + 1]; a2 += xv.w * Wg[(i0 + 3) * HOPS + 2];

        #pragma unroll
        for (int off = 32; off >= 1; off >>= 1) {
            a0 += __shfl_xor(a0, off);
            a1 += __shfl_xor(a1, off);
            a2 += __shfl_xor(a2, off);
        }
        if (lane == 0) {
            float l0 = a0 + bg[0], l1 = a1 + bg[1], l2 = a2 + bg[2];
            float m = fmaxf(l0, fmaxf(l1, l2));
            float e0 = expf(l0 - m), e1 = expf(l1 - m), e2 = expf(l2 - m);
            float inv = 1.f / (e0 + e1 + e2);
            gw[node * HOPS + 0] = e0 * inv;
            gw[node * HOPS + 1] = e1 * inv;
            gw[node * HOPS + 2] = e2 * inv;
        }
    } else if (blk < NB_GATE + NB_PACKW) {
        // ---- pack W: WT[n][k]; coalesced writes, gather reads (W L2-resident)
        int id = (blk - NB_GATE) * 256 + tid;
        int n = id >> 8;            // 0..511
        int k = id & 255;           // 0..255
        float v = (n < HC) ? Wl[k * HC + n] : Wr[k * HC + (n - HC)];
        WT[(size_t)n * IN_DIM + k] = f2bf(v);
    } else {
        // ---- zero cnt (folded memset; completes before gemm_scatter's atomics)
        int id = (blk - NB_GATE - NB_PACKW) * 256 + tid;
        if (id < HOPS * N_NODES) cnt[id] = 0;
    }
}

// ---------------------------------------------------------------------------
// gemm_scatter: gemm v1 (128x128, TK=32) on blocks [0,1568) with XCD-aware
// ordering (blk%8 = XCD slot; each XCD runs by=0..3 of one bx consecutively
// so the A tile is L2-hot for 3 of 4 passes) + edge bucket scatter on
// blocks [1568, 6451) running in the gemm's shadow (independent data).
// ---------------------------------------------------------------------------
#define TM 128
#define TN 128
#define TK 32
#define LDP 40

__global__ __launch_bounds__(256) void gemm_scatter(
    const ushort* __restrict__ Xb, const ushort* __restrict__ WT,
    const float* __restrict__ b_l, const float* __restrict__ b_r,
    ushort* __restrict__ xlb, ushort* __restrict__ xrb, int M,
    const int* __restrict__ ei0, const int* __restrict__ ei1,
    const int* __restrict__ ei2, int* __restrict__ cnt,
    int* __restrict__ bucket)
{
    __shared__ ushort As[TM][LDP];
    __shared__ ushort Bs[TN][LDP];
    const int blk = blockIdx.x;
    const int tid = threadIdx.x;

    if (blk >= GEMM_BLKS) {
        // ---- direct bucket scatter ----
        int f = (blk - GEMM_BLKS) * 256 + tid;
        if (f >= TOT_E) return;
        int k, e; decode_flat(f, k, e);
        int s, d;
        if (k == 0 && e >= EDGES) { s = d = e - EDGES; }
        else {
            const int* ei = (k == 0) ? ei0 : (k == 1) ? ei1 : ei2;
            s = ei[e]; d = ei[EDGES + e];
        }
        int pos = atomicAdd(&cnt[k * N_NODES + d], 1);
        if (pos < CAP)
            bucket[((size_t)k * N_NODES + d) * CAP + pos] = s;
        return;
    }

    // ---- gemm v1, XCD-aware decomposition ----
    // blk = g*32 + by*8 + x  ->  bx = g*8 + x. XCD x sees by=0..3 of bx
    // back-to-back -> As rows L2-resident across the 4 col-passes.
    const int x  = blk & 7;
    const int by = (blk >> 3) & 3;
    const int bx = (blk >> 5) * 8 + x;
    if (bx >= GEMM_BX) return;           // 4 idle tail blocks
    const int wave = tid >> 6, lane = tid & 63;
    const int row0 = bx * TM;
    const int col0 = by * TN;
    const int wy = (wave >> 1) * 64, wx = (wave & 1) * 64;
    const int lrow = lane & 15, lk = (lane >> 4) * 8;

    floatx4 acc[4][4];
    #pragma unroll
    for (int i = 0; i < 4; i++)
        #pragma unroll
        for (int j = 0; j < 4; j++)
            acc[i][j] = (floatx4){0.f, 0.f, 0.f, 0.f};

    for (int k0 = 0; k0 < IN_DIM; k0 += TK) {
        #pragma unroll
        for (int j = 0; j < 2; j++) {
            int id = tid + 256 * j;
            int r  = id >> 2;
            int c  = (id & 3) * 8;
            int gr = row0 + r;
            uint4 v = make_uint4(0u, 0u, 0u, 0u);
            if (gr < M)
                v = *(const uint4*)(Xb + (size_t)gr * IN_DIM + k0 + c);
            *(uint4*)&As[r][c] = v;
        }
        #pragma unroll
        for (int j = 0; j < 2; j++) {
            int id = tid + 256 * j;
            int r  = id >> 2;
            int c  = (id & 3) * 8;
            *(uint4*)&Bs[r][c] =
                *(const uint4*)(WT + (size_t)(col0 + r) * IN_DIM + k0 + c);
        }
        __syncthreads();

        short8 af[4], bf[4];
        #pragma unroll
        for (int mi = 0; mi < 4; mi++)
            af[mi] = *(const short8*)&As[wy + mi * 16 + lrow][lk];
        #pragma unroll
        for (int ni = 0; ni < 4; ni++)
            bf[ni] = *(const short8*)&Bs[wx + ni * 16 + lrow][lk];

        #pragma unroll
        for (int mi = 0; mi < 4; mi++)
            #pragma unroll
            for (int ni = 0; ni < 4; ni++)
                acc[mi][ni] = __builtin_amdgcn_mfma_f32_16x16x32_bf16(
                    bf[ni], af[mi], acc[mi][ni], 0, 0, 0);
        __syncthreads();
    }

    const int csub = (lane >> 4) * 4;
    #pragma unroll
    for (int mi = 0; mi < 4; mi++) {
        int grow = row0 + wy + mi * 16 + lrow;
        if (grow < M) {
            #pragma unroll
            for (int ni = 0; ni < 4; ni++) {
                int gcol = col0 + wx + ni * 16 + csub;
                floatx4 v = acc[mi][ni];
                const bool left = (gcol < HC);
                const float4 b = left ? *(const float4*)(b_l + gcol)
                                      : *(const float4*)(b_r + gcol - HC);
                union { ushort s[4]; uint2 u; } o;
                o.s[0] = f2bf(v[0] + b.x);
                o.s[1] = f2bf(v[1] + b.y);
                o.s[2] = f2bf(v[2] + b.z);
                o.s[3] = f2bf(v[3] + b.w);
                ushort* dst = left ? (xlb + (size_t)grow * HC + gcol)
                                   : (xrb + (size_t)grow * HC + gcol - HC);
                *(uint2*)dst = o.u;
            }
        }
    }
}

// ---------------------------------------------------------------------------
// node_all v7+exp2 (structure unchanged — 141.5 µs, BW-bound on random
// gathers): att pre-scaled by log2(e) so the softmax exp is a bare
// v_exp_f32 (exp2f). One 192-thread block (3 waves) per node.
// ---------------------------------------------------------------------------
__global__ __launch_bounds__(192) void node_all(
    const ushort* __restrict__ xlb, const ushort* __restrict__ xrb,
    const int* __restrict__ cnt, const int* __restrict__ bucket,
    const float* __restrict__ att, const float* __restrict__ gw,
    const float* __restrict__ bias, float* __restrict__ out)
{
    __shared__ float lds[HOPS][CDIM];
    const int n    = blockIdx.x;
    const int k    = threadIdx.x >> 6;   // hop
    const int lane = threadIdx.x & 63;
    const int half = lane >> 5;          // which edge of the pair
    const int sub  = lane & 31;          // channel group: ch = sub*8 .. sub*8+7
    const unsigned laneoff = (unsigned)sub * 8;

    const int deg = min(cnt[k * N_NODES + n], CAP);
    const int* bk = bucket + ((size_t)k * N_NODES + n) * CAP;

    // xr channels for this lane (bf16 -> f32x2 pairs)
    uint4 rq = *(const uint4*)(xrb + (size_t)n * HC + laneoff);
    f32x2 rr[4] = { bf2x(rq.x), bf2x(rq.y), bf2x(rq.z), bf2x(rq.w) };

    // att pre-scaled by LOG2E: p is then a log2-domain logit -> exp2f(p)
    const float4 a0 = ((const float4*)(att + (size_t)k * HC))[sub * 2 + 0];
    const float4 a1 = ((const float4*)(att + (size_t)k * HC))[sub * 2 + 1];
    f32x2 w2[4] = { {a0.x * LOG2E, a0.y * LOG2E}, {a0.z * LOG2E, a0.w * LOG2E},
                    {a1.x * LOG2E, a1.y * LOG2E}, {a1.z * LOG2E, a1.w * LOG2E} };

    float denom = 0.f;
    f32x2 acc2[4] = { {0.f,0.f}, {0.f,0.f}, {0.f,0.f}, {0.f,0.f} };

    if (deg > 0) {
        const int degm1 = deg - 1;
        int myS = (lane < deg) ? bk[lane] : 0;
        const int npair = (deg + 1) >> 1;

        int s0 = __shfl(myS, min(half, degm1));
        uint4 q = *(const uint4*)(xlb + (unsigned)s0 * HC + laneoff);

        for (int j = 0; j < npair; j++) {
            int sn = __shfl(myS, min(2 * (j + 1) + half, degm1));
            uint4 qn = *(const uint4*)(xlb + (unsigned)sn * HC + laneoff);

            f32x2 f0 = bf2x(q.x), f1 = bf2x(q.y);
            f32x2 f2 = bf2x(q.z), f3 = bf2x(q.w);

            f32x2 pp = w2[0] * lrelu2(f0 + rr[0]);
            pp = __builtin_elementwise_fma(w2[1], lrelu2(f1 + rr[1]), pp);
            pp = __builtin_elementwise_fma(w2[2], lrelu2(f2 + rr[2]), pp);
            pp = __builtin_elementwise_fma(w2[3], lrelu2(f3 + rr[3]), pp);
            float p = pp.x + pp.y;

            // per-head reduce: head = 8 consecutive lanes (within half)
            p += __shfl_xor(p, 1);
            p += __shfl_xor(p, 2);
            p += __shfl_xor(p, 4);

            bool valid = (2 * j + half) < deg;
            float ex = valid ? exp2f(p) : 0.f;
            denom += ex;
            f32x2 ex2 = { ex, ex };
            acc2[0] = __builtin_elementwise_fma(ex2, f0, acc2[0]);
            acc2[1] = __builtin_elementwise_fma(ex2, f1, acc2[1]);
            acc2[2] = __builtin_elementwise_fma(ex2, f2, acc2[2]);
            acc2[3] = __builtin_elementwise_fma(ex2, f3, acc2[3]);
            q = qn;
        }
    }

    // merge halves (xor-32): denom & acc are per-head after this.
    denom += __shfl_xor(denom, 32);
    const float inv = (denom > 0.f) ? 1.f / denom : 0.f;
    const float g   = gw[n * HOPS + k];
    const float* bb = bias + (size_t)k * CDIM + (size_t)(sub & 7) * 8;

    // per-head normalize FIRST (each lane still carries its own head),
    // THEN head mean across lanes {sub&7, +8, +16, +24} (xor-8, xor-16).
    #pragma unroll
    for (int i = 0; i < 4; i++) {
        acc2[i].x += __shfl_xor(acc2[i].x, 32);
        acc2[i].y += __shfl_xor(acc2[i].y, 32);
        acc2[i].x *= inv;
        acc2[i].y *= inv;
        acc2[i].x += __shfl_xor(acc2[i].x, 8);
        acc2[i].y += __shfl_xor(acc2[i].y, 8);
        acc2[i].x += __shfl_xor(acc2[i].x, 16);
        acc2[i].y += __shfl_xor(acc2[i].y, 16);
        if (lane < 8) {
            lds[k][lane * 8 + 2 * i]     = g * (acc2[i].x * 0.25f + bb[2 * i]);
            lds[k][lane * 8 + 2 * i + 1] = g * (acc2[i].y * 0.25f + bb[2 * i + 1]);
        }
    }
    __syncthreads();

    if (threadIdx.x < CDIM)
        out[(size_t)n * CDIM + threadIdx.x] =
            lds[0][threadIdx.x] + lds[1][threadIdx.x] + lds[2][threadIdx.x];
}

// ---------------------------------------------------------------------------
extern "C" void kernel_launch(void* const* d_in, const int* in_sizes, int n_in,
                              void* d_out, int out_size, void* d_ws, size_t ws_size,
                              hipStream_t stream)
{
    const float* x      = (const float*)d_in[0];
    const int*   ei0    = (const int*)d_in[1];
    const int*   ei1    = (const int*)d_in[2];
    const int*   ei2    = (const int*)d_in[3];
    const float* W_l    = (const float*)d_in[4];
    const float* b_l    = (const float*)d_in[5];
    const float* W_r    = (const float*)d_in[6];
    const float* b_r    = (const float*)d_in[7];
    const float* att    = (const float*)d_in[8];   // [3,4,64]
    const float* bias   = (const float*)d_in[9];   // [3,64]
    const float* W_gate = (const float*)d_in[10];  // [256,3]
    const float* b_gate = (const float*)d_in[11];  // [3]

    const size_t NHC = (size_t)N_NODES * HC;       // 12,800,000
    float* ws      = (float*)d_ws;
    float* gwbuf   = ws;                           // 150,000 floats
    int*   cnt     = (int*)(gwbuf + HOPS * N_NODES);         // 150,000 ints
    int*   bucket  = cnt + HOPS * N_NODES;         // 3*N*CAP = 6,000,000 ints
    ushort* xlb    = (ushort*)(bucket + (size_t)HOPS * N_NODES * CAP); // NHC bf16
    ushort* xrb    = xlb + NHC;                    // NHC bf16
    ushort* Xb     = xrb + NHC;                    // NHC bf16
    ushort* WT     = Xb + NHC;                     // 131,072 bf16

    // gate + pack_x | pack_w | zero-cnt (memset folded in; no extra launch)
    prep_a<<<NB_GATE + NB_PACKW + NB_ZERO, 256, 0, stream>>>(
        x, W_gate, b_gate, gwbuf, Xb, W_l, W_r, WT, cnt);

    // gemm v1 (XCD-aware order) + concurrent edge scatter
    gemm_scatter<<<FUSED_BLKS, 256, 0, stream>>>(
        Xb, WT, b_l, b_r, xlb, xrb, N_NODES,
        ei0, ei1, ei2, cnt, bucket);

    // fused logits + softmax + aggregate + head-mean + gate combine
    node_all<<<N_NODES, 192, 0, stream>>>(
        xlb, xrb, cnt, bucket, att, gwbuf, bias, (float*)d_out);
}

// Round 10
// 351.306 us; speedup vs baseline: 1.1128x; 1.0492x over previous
//
#include <hip/hip_runtime.h>
#include <math.h>

#define N_NODES 50000
#define IN_DIM 256
#define HEADS 4
#define CDIM 64
#define HC 256        // HEADS*CDIM
#define HOPS 3
#define EDGES 400000
#define NEG_SLOPE 0.2f
#define SEG (EDGES + N_NODES)            // hop0 flat range incl self-loops
#define TOT_E (3 * EDGES + N_NODES)      // flat edge count across hops
#define CAP 40                           // bucket capacity; P(Poisson(8)+1 > 40) ~ 1e-16
#define LOG2E 1.44269504f

// prep_a kernel block ranges (gate+packx | packw | zero-cnt)
#define NB_GATE  ((N_NODES + 3) / 4)             // 12500
#define NB_PACKW ((IN_DIM * 2 * HC) / 256)       // 512
#define NB_ZERO  ((HOPS * N_NODES + 255) / 256)  // 587
#define NB_SCAT  ((TOT_E + 255) / 256)           // 4883
// gemm v1 shape; XCD-aware 1D order: 32-block groups = 8 XCD x 4 col-blocks,
// so one XCD sees all 4 by of a given bx consecutively -> A-tile L2 reuse.
#define GEMM_BX    ((N_NODES + 127) / 128)       // 391
#define GEMM_GRP   ((GEMM_BX + 7) / 8)           // 49
#define GEMM_BLKS  (GEMM_GRP * 32)               // 1568 (4 idle tail blocks)
#define FUSED_BLKS (GEMM_BLKS + NB_SCAT)         // 6451

typedef unsigned short ushort;
using short8  = __attribute__((ext_vector_type(8))) short;
using floatx4 = __attribute__((ext_vector_type(4))) float;
using f32x2   = __attribute__((ext_vector_type(2))) float;

// flat layout: hop0 [0, E+N) incl self-loops ; hop1 [SEG, SEG+E) ; hop2 [...]
__device__ __forceinline__ void decode_flat(int f, int& k, int& e)
{
    if (f < SEG)              { k = 0; e = f; }
    else if (f < SEG + EDGES) { k = 1; e = f - SEG; }
    else                      { k = 2; e = f - SEG - EDGES; }
}

__device__ __forceinline__ ushort f2bf(float f)
{
    unsigned u = __float_as_uint(f);
    unsigned r = u + 0x7fffu + ((u >> 16) & 1u);   // RNE
    return (ushort)(r >> 16);
}

// raw v_exp_f32: D = 2^S0 (no libm fixup; matches __expf's internal use)
__device__ __forceinline__ float exp2_raw(float x)
{
    float r;
    asm volatile("v_exp_f32 %0, %1" : "=v"(r) : "v"(x));
    return r;
}

// unpack 2 bf16 (packed in a uint) -> f32x2 {lo, hi}
__device__ __forceinline__ f32x2 bf2x(unsigned u)
{
    f32x2 r;
    r.x = __uint_as_float(u << 16);
    r.y = __uint_as_float(u & 0xffff0000u);
    return r;
}

// leaky-relu slope 0.2: max(v, 0.2v)  -> v_pk_mul_f32 + v_pk_max_f32
// (VOP3P has no abs input modifier, so this 2-op form is packed-minimal)
__device__ __forceinline__ f32x2 lrelu2(f32x2 v)
{
    return __builtin_elementwise_max(v, 0.2f * v);
}

// ---------------------------------------------------------------------------
// prep_a: [gate+pack_x | pack_w | zero-cnt]. The cnt memset is folded in as a
// block range (saves one launch); the edge scatter lives in gemm_scatter.
// ---------------------------------------------------------------------------
__global__ __launch_bounds__(256) void prep_a(
    const float* __restrict__ X, const float* __restrict__ Wg,
    const float* __restrict__ bg, float* __restrict__ gw,
    ushort* __restrict__ Xb,
    const float* __restrict__ Wl, const float* __restrict__ Wr,
    ushort* __restrict__ WT, int* __restrict__ cnt)
{
    const int blk = blockIdx.x;
    const int tid = threadIdx.x;

    if (blk < NB_GATE) {
        // ---- gate + bf16 pack of x: one wave per node ----
        const int node = (blk * 256 + tid) >> 6;
        const int lane = tid & 63;
        if (node >= N_NODES) return;

        float4 xv = ((const float4*)(X + (size_t)node * IN_DIM))[lane];

        union { ushort s[4]; uint2 u; } o;
        o.s[0] = f2bf(xv.x); o.s[1] = f2bf(xv.y);
        o.s[2] = f2bf(xv.z); o.s[3] = f2bf(xv.w);
        ((uint2*)(Xb + (size_t)node * IN_DIM))[lane] = o.u;

        float a0 = 0.f, a1 = 0.f, a2 = 0.f;
        const int i0 = lane * 4;
        a0 += xv.x * Wg[(i0 + 0) * HOPS + 0]; a1 += xv.x * Wg[(i0 + 0) * HOPS + 1]; a2 += xv.x * Wg[(i0 + 0) * HOPS + 2];
        a0 += xv.y * Wg[(i0 + 1) * HOPS + 0]; a1 += xv.y * Wg[(i0 + 1) * HOPS + 1]; a2 += xv.y * Wg[(i0 + 1) * HOPS + 2];
        a0 += xv.z * Wg[(i0 + 2) * HOPS + 0]; a1 += xv.z * Wg[(i0 + 2) * HOPS + 1]; a2 += xv.z * Wg[(i0 + 2) * HOPS + 2];
        a0 += xv.w * Wg[(i0 + 3) * HOPS + 0]; a1 += xv.w * Wg[(i0 + 3) * HOPS + 1]; a2 += xv.w * Wg[(i0 + 3) * HOPS + 2];

        #pragma unroll
        for (int off = 32; off >= 1; off >>= 1) {
            a0 += __shfl_xor(a0, off);
            a1 += __shfl_xor(a1, off);
            a2 += __shfl_xor(a2, off);
        }
        if (lane == 0) {
            float l0 = a0 + bg[0], l1 = a1 + bg[1], l2 = a2 + bg[2];
            float m = fmaxf(l0, fmaxf(l1, l2));
            float e0 = expf(l0 - m), e1 = expf(l1 - m), e2 = expf(l2 - m);
            float inv = 1.f / (e0 + e1 + e2);
            gw[node * HOPS + 0] = e0 * inv;
            gw[node * HOPS + 1] = e1 * inv;
            gw[node * HOPS + 2] = e2 * inv;
        }
    } else if (blk < NB_GATE + NB_PACKW) {
        // ---- pack W: WT[n][k]; coalesced writes, gather reads (W L2-resident)
        int id = (blk - NB_GATE) * 256 + tid;
        int n = id >> 8;            // 0..511
        int k = id & 255;           // 0..255
        float v = (n < HC) ? Wl[k * HC + n] : Wr[k * HC + (n - HC)];
        WT[(size_t)n * IN_DIM + k] = f2bf(v);
    } else {
        // ---- zero cnt (folded memset; completes before gemm_scatter's atomics)
        int id = (blk - NB_GATE - NB_PACKW) * 256 + tid;
        if (id < HOPS * N_NODES) cnt[id] = 0;
    }
}

// ---------------------------------------------------------------------------
// gemm_scatter: gemm v1 (128x128, TK=32) on blocks [0,1568) with XCD-aware
// ordering (blk%8 = XCD slot; each XCD runs by=0..3 of one bx consecutively
// so the A tile is L2-hot for 3 of 4 passes) + edge bucket scatter on
// blocks [1568, 6451) running in the gemm's shadow (independent data).
// ---------------------------------------------------------------------------
#define TM 128
#define TN 128
#define TK 32
#define LDP 40

__global__ __launch_bounds__(256) void gemm_scatter(
    const ushort* __restrict__ Xb, const ushort* __restrict__ WT,
    const float* __restrict__ b_l, const float* __restrict__ b_r,
    ushort* __restrict__ xlb, ushort* __restrict__ xrb, int M,
    const int* __restrict__ ei0, const int* __restrict__ ei1,
    const int* __restrict__ ei2, int* __restrict__ cnt,
    int* __restrict__ bucket)
{
    __shared__ ushort As[TM][LDP];
    __shared__ ushort Bs[TN][LDP];
    const int blk = blockIdx.x;
    const int tid = threadIdx.x;

    if (blk >= GEMM_BLKS) {
        // ---- direct bucket scatter ----
        int f = (blk - GEMM_BLKS) * 256 + tid;
        if (f >= TOT_E) return;
        int k, e; decode_flat(f, k, e);
        int s, d;
        if (k == 0 && e >= EDGES) { s = d = e - EDGES; }
        else {
            const int* ei = (k == 0) ? ei0 : (k == 1) ? ei1 : ei2;
            s = ei[e]; d = ei[EDGES + e];
        }
        int pos = atomicAdd(&cnt[k * N_NODES + d], 1);
        if (pos < CAP)
            bucket[((size_t)k * N_NODES + d) * CAP + pos] = s;
        return;
    }

    // ---- gemm v1, XCD-aware decomposition ----
    // blk = g*32 + by*8 + x  ->  bx = g*8 + x. XCD x sees by=0..3 of bx
    // back-to-back -> As rows L2-resident across the 4 col-passes.
    const int x  = blk & 7;
    const int by = (blk >> 3) & 3;
    const int bx = (blk >> 5) * 8 + x;
    if (bx >= GEMM_BX) return;           // 4 idle tail blocks
    const int wave = tid >> 6, lane = tid & 63;
    const int row0 = bx * TM;
    const int col0 = by * TN;
    const int wy = (wave >> 1) * 64, wx = (wave & 1) * 64;
    const int lrow = lane & 15, lk = (lane >> 4) * 8;

    floatx4 acc[4][4];
    #pragma unroll
    for (int i = 0; i < 4; i++)
        #pragma unroll
        for (int j = 0; j < 4; j++)
            acc[i][j] = (floatx4){0.f, 0.f, 0.f, 0.f};

    for (int k0 = 0; k0 < IN_DIM; k0 += TK) {
        #pragma unroll
        for (int j = 0; j < 2; j++) {
            int id = tid + 256 * j;
            int r  = id >> 2;
            int c  = (id & 3) * 8;
            int gr = row0 + r;
            uint4 v = make_uint4(0u, 0u, 0u, 0u);
            if (gr < M)
                v = *(const uint4*)(Xb + (size_t)gr * IN_DIM + k0 + c);
            *(uint4*)&As[r][c] = v;
        }
        #pragma unroll
        for (int j = 0; j < 2; j++) {
            int id = tid + 256 * j;
            int r  = id >> 2;
            int c  = (id & 3) * 8;
            *(uint4*)&Bs[r][c] =
                *(const uint4*)(WT + (size_t)(col0 + r) * IN_DIM + k0 + c);
        }
        __syncthreads();

        short8 af[4], bf[4];
        #pragma unroll
        for (int mi = 0; mi < 4; mi++)
            af[mi] = *(const short8*)&As[wy + mi * 16 + lrow][lk];
        #pragma unroll
        for (int ni = 0; ni < 4; ni++)
            bf[ni] = *(const short8*)&Bs[wx + ni * 16 + lrow][lk];

        #pragma unroll
        for (int mi = 0; mi < 4; mi++)
            #pragma unroll
            for (int ni = 0; ni < 4; ni++)
                acc[mi][ni] = __builtin_amdgcn_mfma_f32_16x16x32_bf16(
                    bf[ni], af[mi], acc[mi][ni], 0, 0, 0);
        __syncthreads();
    }

    const int csub = (lane >> 4) * 4;
    #pragma unroll
    for (int mi = 0; mi < 4; mi++) {
        int grow = row0 + wy + mi * 16 + lrow;
        if (grow < M) {
            #pragma unroll
            for (int ni = 0; ni < 4; ni++) {
                int gcol = col0 + wx + ni * 16 + csub;
                floatx4 v = acc[mi][ni];
                const bool left = (gcol < HC);
                const float4 b = left ? *(const float4*)(b_l + gcol)
                                      : *(const float4*)(b_r + gcol - HC);
                union { ushort s[4]; uint2 u; } o;
                o.s[0] = f2bf(v[0] + b.x);
                o.s[1] = f2bf(v[1] + b.y);
                o.s[2] = f2bf(v[2] + b.z);
                o.s[3] = f2bf(v[3] + b.w);
                ushort* dst = left ? (xlb + (size_t)grow * HC + gcol)
                                   : (xrb + (size_t)grow * HC + gcol - HC);
                *(uint2*)dst = o.u;
            }
        }
    }
}

// ---------------------------------------------------------------------------
// node_all v9: v7 structure + att pre-scaled by log2(e) + RAW v_exp_f32
// (inline asm) for the softmax exp. exp2f() regressed (+4 µs: libm fixup
// code around v_exp); raw v_exp = __expf minus the per-pair v_mul.
// One 192-thread block (3 waves) per node; wave k = hop k.
// ---------------------------------------------------------------------------
__global__ __launch_bounds__(192) void node_all(
    const ushort* __restrict__ xlb, const ushort* __restrict__ xrb,
    const int* __restrict__ cnt, const int* __restrict__ bucket,
    const float* __restrict__ att, const float* __restrict__ gw,
    const float* __restrict__ bias, float* __restrict__ out)
{
    __shared__ float lds[HOPS][CDIM];
    const int n    = blockIdx.x;
    const int k    = threadIdx.x >> 6;   // hop
    const int lane = threadIdx.x & 63;
    const int half = lane >> 5;          // which edge of the pair
    const int sub  = lane & 31;          // channel group: ch = sub*8 .. sub*8+7
    const unsigned laneoff = (unsigned)sub * 8;

    const int deg = min(cnt[k * N_NODES + n], CAP);
    const int* bk = bucket + ((size_t)k * N_NODES + n) * CAP;

    // xr channels for this lane (bf16 -> f32x2 pairs)
    uint4 rq = *(const uint4*)(xrb + (size_t)n * HC + laneoff);
    f32x2 rr[4] = { bf2x(rq.x), bf2x(rq.y), bf2x(rq.z), bf2x(rq.w) };

    // att pre-scaled by LOG2E: p is a log2-domain logit -> raw v_exp_f32
    const float4 a0 = ((const float4*)(att + (size_t)k * HC))[sub * 2 + 0];
    const float4 a1 = ((const float4*)(att + (size_t)k * HC))[sub * 2 + 1];
    f32x2 w2[4] = { {a0.x * LOG2E, a0.y * LOG2E}, {a0.z * LOG2E, a0.w * LOG2E},
                    {a1.x * LOG2E, a1.y * LOG2E}, {a1.z * LOG2E, a1.w * LOG2E} };

    float denom = 0.f;
    f32x2 acc2[4] = { {0.f,0.f}, {0.f,0.f}, {0.f,0.f}, {0.f,0.f} };

    if (deg > 0) {
        const int degm1 = deg - 1;
        int myS = (lane < deg) ? bk[lane] : 0;
        const int npair = (deg + 1) >> 1;

        int s0 = __shfl(myS, min(half, degm1));
        uint4 q = *(const uint4*)(xlb + (unsigned)s0 * HC + laneoff);

        for (int j = 0; j < npair; j++) {
            int sn = __shfl(myS, min(2 * (j + 1) + half, degm1));
            uint4 qn = *(const uint4*)(xlb + (unsigned)sn * HC + laneoff);

            f32x2 f0 = bf2x(q.x), f1 = bf2x(q.y);
            f32x2 f2 = bf2x(q.z), f3 = bf2x(q.w);

            f32x2 pp = w2[0] * lrelu2(f0 + rr[0]);
            pp = __builtin_elementwise_fma(w2[1], lrelu2(f1 + rr[1]), pp);
            pp = __builtin_elementwise_fma(w2[2], lrelu2(f2 + rr[2]), pp);
            pp = __builtin_elementwise_fma(w2[3], lrelu2(f3 + rr[3]), pp);
            float p = pp.x + pp.y;

            // per-head reduce: head = 8 consecutive lanes (within half)
            p += __shfl_xor(p, 1);
            p += __shfl_xor(p, 2);
            p += __shfl_xor(p, 4);

            bool valid = (2 * j + half) < deg;
            float ex = valid ? exp2_raw(p) : 0.f;
            denom += ex;
            f32x2 ex2 = { ex, ex };
            acc2[0] = __builtin_elementwise_fma(ex2, f0, acc2[0]);
            acc2[1] = __builtin_elementwise_fma(ex2, f1, acc2[1]);
            acc2[2] = __builtin_elementwise_fma(ex2, f2, acc2[2]);
            acc2[3] = __builtin_elementwise_fma(ex2, f3, acc2[3]);
            q = qn;
        }
    }

    // merge halves (xor-32): denom & acc are per-head after this.
    denom += __shfl_xor(denom, 32);
    const float inv = (denom > 0.f) ? 1.f / denom : 0.f;
    const float g   = gw[n * HOPS + k];
    const float* bb = bias + (size_t)k * CDIM + (size_t)(sub & 7) * 8;

    // per-head normalize FIRST (each lane still carries its own head),
    // THEN head mean across lanes {sub&7, +8, +16, +24} (xor-8, xor-16).
    #pragma unroll
    for (int i = 0; i < 4; i++) {
        acc2[i].x += __shfl_xor(acc2[i].x, 32);
        acc2[i].y += __shfl_xor(acc2[i].y, 32);
        acc2[i].x *= inv;
        acc2[i].y *= inv;
        acc2[i].x += __shfl_xor(acc2[i].x, 8);
        acc2[i].y += __shfl_xor(acc2[i].y, 8);
        acc2[i].x += __shfl_xor(acc2[i].x, 16);
        acc2[i].y += __shfl_xor(acc2[i].y, 16);
        if (lane < 8) {
            lds[k][lane * 8 + 2 * i]     = g * (acc2[i].x * 0.25f + bb[2 * i]);
            lds[k][lane * 8 + 2 * i + 1] = g * (acc2[i].y * 0.25f + bb[2 * i + 1]);
        }
    }
    __syncthreads();

    if (threadIdx.x < CDIM)
        out[(size_t)n * CDIM + threadIdx.x] =
            lds[0][threadIdx.x] + lds[1][threadIdx.x] + lds[2][threadIdx.x];
}

// ---------------------------------------------------------------------------
extern "C" void kernel_launch(void* const* d_in, const int* in_sizes, int n_in,
                              void* d_out, int out_size, void* d_ws, size_t ws_size,
                              hipStream_t stream)
{
    const float* x      = (const float*)d_in[0];
    const int*   ei0    = (const int*)d_in[1];
    const int*   ei1    = (const int*)d_in[2];
    const int*   ei2    = (const int*)d_in[3];
    const float* W_l    = (const float*)d_in[4];
    const float* b_l    = (const float*)d_in[5];
    const float* W_r    = (const float*)d_in[6];
    const float* b_r    = (const float*)d_in[7];
    const float* att    = (const float*)d_in[8];   // [3,4,64]
    const float* bias   = (const float*)d_in[9];   // [3,64]
    const float* W_gate = (const float*)d_in[10];  // [256,3]
    const float* b_gate = (const float*)d_in[11];  // [3]

    const size_t NHC = (size_t)N_NODES * HC;       // 12,800,000
    float* ws      = (float*)d_ws;
    float* gwbuf   = ws;                           // 150,000 floats
    int*   cnt     = (int*)(gwbuf + HOPS * N_NODES);         // 150,000 ints
    int*   bucket  = cnt + HOPS * N_NODES;         // 3*N*CAP = 6,000,000 ints
    ushort* xlb    = (ushort*)(bucket + (size_t)HOPS * N_NODES * CAP); // NHC bf16
    ushort* xrb    = xlb + NHC;                    // NHC bf16
    ushort* Xb     = xrb + NHC;                    // NHC bf16
    ushort* WT     = Xb + NHC;                     // 131,072 bf16

    // gate + pack_x | pack_w | zero-cnt (memset folded in; no extra launch)
    prep_a<<<NB_GATE + NB_PACKW + NB_ZERO, 256, 0, stream>>>(
        x, W_gate, b_gate, gwbuf, Xb, W_l, W_r, WT, cnt);

    // gemm v1 (XCD-aware order) + concurrent edge scatter
    gemm_scatter<<<FUSED_BLKS, 256, 0, stream>>>(
        Xb, WT, b_l, b_r, xlb, xrb, N_NODES,
        ei0, ei1, ei2, cnt, bucket);

    // fused logits + softmax + aggregate + head-mean + gate combine
    node_all<<<N_NODES, 192, 0, stream>>>(
        xlb, xrb, cnt, bucket, att, gwbuf, bias, (float*)d_out);
}

// Round 11
// 346.616 us; speedup vs baseline: 1.1279x; 1.0135x over previous
//
#include <hip/hip_runtime.h>
#include <math.h>

#define N_NODES 50000
#define IN_DIM 256
#define HEADS 4
#define CDIM 64
#define HC 256        // HEADS*CDIM
#define HOPS 3
#define EDGES 400000
#define NEG_SLOPE 0.2f
#define SEG (EDGES + N_NODES)            // hop0 flat range incl self-loops
#define TOT_E (3 * EDGES + N_NODES)      // flat edge count across hops
#define CAP 40                           // bucket capacity; P(Poisson(8)+1 > 40) ~ 1e-16
#define LOG2E 1.44269504f

// prep_a kernel block ranges (gate+packx | packw | zero-cnt)
#define NB_GATE  ((N_NODES + 3) / 4)             // 12500
#define NB_PACKW ((IN_DIM * 2 * HC) / 256)       // 512
#define NB_ZERO  ((HOPS * N_NODES + 255) / 256)  // 587
#define NB_SCAT  ((TOT_E + 255) / 256)           // 4883
// gemm v4: 64 rows x full 512 cols per block; A LDS once (full K), B direct
// from L2 (WT = 256 KB, L2-resident); NO barriers in the K-loop.
#define GB 64
#define AP 264                                   // A row pad: 132-dw stride -> 2-way free
#define GEMM_BLKS  ((N_NODES + GB - 1) / GB)     // 782
#define FUSED_BLKS (GEMM_BLKS + NB_SCAT)         // 5665

typedef unsigned short ushort;
using short8  = __attribute__((ext_vector_type(8))) short;
using floatx4 = __attribute__((ext_vector_type(4))) float;
using f32x2   = __attribute__((ext_vector_type(2))) float;

// flat layout: hop0 [0, E+N) incl self-loops ; hop1 [SEG, SEG+E) ; hop2 [...]
__device__ __forceinline__ void decode_flat(int f, int& k, int& e)
{
    if (f < SEG)              { k = 0; e = f; }
    else if (f < SEG + EDGES) { k = 1; e = f - SEG; }
    else                      { k = 2; e = f - SEG - EDGES; }
}

__device__ __forceinline__ ushort f2bf(float f)
{
    unsigned u = __float_as_uint(f);
    unsigned r = u + 0x7fffu + ((u >> 16) & 1u);   // RNE
    return (ushort)(r >> 16);
}

// raw v_exp_f32: D = 2^S0 (no libm fixup; matches __expf's internal use)
__device__ __forceinline__ float exp2_raw(float x)
{
    float r;
    asm volatile("v_exp_f32 %0, %1" : "=v"(r) : "v"(x));
    return r;
}

// unpack 2 bf16 (packed in a uint) -> f32x2 {lo, hi}
__device__ __forceinline__ f32x2 bf2x(unsigned u)
{
    f32x2 r;
    r.x = __uint_as_float(u << 16);
    r.y = __uint_as_float(u & 0xffff0000u);
    return r;
}

// leaky-relu slope 0.2: max(v, 0.2v)  -> v_pk_mul_f32 + v_pk_max_f32
__device__ __forceinline__ f32x2 lrelu2(f32x2 v)
{
    return __builtin_elementwise_max(v, 0.2f * v);
}

// ---------------------------------------------------------------------------
// prep_a: [gate+pack_x | pack_w | zero-cnt] (unchanged from r10 winner).
// ---------------------------------------------------------------------------
__global__ __launch_bounds__(256) void prep_a(
    const float* __restrict__ X, const float* __restrict__ Wg,
    const float* __restrict__ bg, float* __restrict__ gw,
    ushort* __restrict__ Xb,
    const float* __restrict__ Wl, const float* __restrict__ Wr,
    ushort* __restrict__ WT, int* __restrict__ cnt)
{
    const int blk = blockIdx.x;
    const int tid = threadIdx.x;

    if (blk < NB_GATE) {
        // ---- gate + bf16 pack of x: one wave per node ----
        const int node = (blk * 256 + tid) >> 6;
        const int lane = tid & 63;
        if (node >= N_NODES) return;

        float4 xv = ((const float4*)(X + (size_t)node * IN_DIM))[lane];

        union { ushort s[4]; uint2 u; } o;
        o.s[0] = f2bf(xv.x); o.s[1] = f2bf(xv.y);
        o.s[2] = f2bf(xv.z); o.s[3] = f2bf(xv.w);
        ((uint2*)(Xb + (size_t)node * IN_DIM))[lane] = o.u;

        float a0 = 0.f, a1 = 0.f, a2 = 0.f;
        const int i0 = lane * 4;
        a0 += xv.x * Wg[(i0 + 0) * HOPS + 0]; a1 += xv.x * Wg[(i0 + 0) * HOPS + 1]; a2 += xv.x * Wg[(i0 + 0) * HOPS + 2];
        a0 += xv.y * Wg[(i0 + 1) * HOPS + 0]; a1 += xv.y * Wg[(i0 + 1) * HOPS + 1]; a2 += xv.y * Wg[(i0 + 1) * HOPS + 2];
        a0 += xv.z * Wg[(i0 + 2) * HOPS + 0]; a1 += xv.z * Wg[(i0 + 2) * HOPS + 1]; a2 += xv.z * Wg[(i0 + 2) * HOPS + 2];
        a0 += xv.w * Wg[(i0 + 3) * HOPS + 0]; a1 += xv.w * Wg[(i0 + 3) * HOPS + 1]; a2 += xv.w * Wg[(i0 + 3) * HOPS + 2];

        #pragma unroll
        for (int off = 32; off >= 1; off >>= 1) {
            a0 += __shfl_xor(a0, off);
            a1 += __shfl_xor(a1, off);
            a2 += __shfl_xor(a2, off);
        }
        if (lane == 0) {
            float l0 = a0 + bg[0], l1 = a1 + bg[1], l2 = a2 + bg[2];
            float m = fmaxf(l0, fmaxf(l1, l2));
            float e0 = expf(l0 - m), e1 = expf(l1 - m), e2 = expf(l2 - m);
            float inv = 1.f / (e0 + e1 + e2);
            gw[node * HOPS + 0] = e0 * inv;
            gw[node * HOPS + 1] = e1 * inv;
            gw[node * HOPS + 2] = e2 * inv;
        }
    } else if (blk < NB_GATE + NB_PACKW) {
        // ---- pack W: WT[n][k]; coalesced writes, gather reads (W L2-resident)
        int id = (blk - NB_GATE) * 256 + tid;
        int n = id >> 8;            // 0..511
        int k = id & 255;           // 0..255
        float v = (n < HC) ? Wl[k * HC + n] : Wr[k * HC + (n - HC)];
        WT[(size_t)n * IN_DIM + k] = f2bf(v);
    } else {
        // ---- zero cnt (folded memset; completes before gemm_scatter's atomics)
        int id = (blk - NB_GATE - NB_PACKW) * 256 + tid;
        if (id < HOPS * N_NODES) cnt[id] = 0;
    }
}

// ---------------------------------------------------------------------------
// gemm_scatter v4: blocks [0,782) = gemm (64 rows x all 512 cols; A staged to
// LDS once full-K; B fragments read DIRECT from L2-resident WT; no K-loop
// barriers). Staged-traffic arithmetic: v1 moved ~205 MB through L3 (A x4 +
// B x391) -> ~130 µs; v4 moves A once (25.6 MB, L3) + B from L2 (~35 TB/s).
// Blocks [782, 5665) = edge bucket scatter (measured ~5-10 µs, overlapped).
// ---------------------------------------------------------------------------
__global__ __launch_bounds__(256, 2) void gemm_scatter(
    const ushort* __restrict__ Xb, const ushort* __restrict__ WT,
    const float* __restrict__ b_l, const float* __restrict__ b_r,
    ushort* __restrict__ xlb, ushort* __restrict__ xrb, int M,
    const int* __restrict__ ei0, const int* __restrict__ ei1,
    const int* __restrict__ ei2, int* __restrict__ cnt,
    int* __restrict__ bucket)
{
    __shared__ ushort As[GB][AP];        // 64 x 264 x 2B = 33,792 B
    const int blk = blockIdx.x;
    const int tid = threadIdx.x;

    if (blk >= GEMM_BLKS) {
        // ---- direct bucket scatter ----
        int f = (blk - GEMM_BLKS) * 256 + tid;
        if (f >= TOT_E) return;
        int k, e; decode_flat(f, k, e);
        int s, d;
        if (k == 0 && e >= EDGES) { s = d = e - EDGES; }
        else {
            const int* ei = (k == 0) ? ei0 : (k == 1) ? ei1 : ei2;
            s = ei[e]; d = ei[EDGES + e];
        }
        int pos = atomicAdd(&cnt[k * N_NODES + d], 1);
        if (pos < CAP)
            bucket[((size_t)k * N_NODES + d) * CAP + pos] = s;
        return;
    }

    const int wave = tid >> 6, lane = tid & 63;
    const int row0 = blk * GB;
    const int wx   = wave * 128;         // this wave's output-col base
    const int lrow = lane & 15, lk = (lane >> 4) * 8;

    // ---- stage full-K A tile once: 64 rows x 256 cols bf16 ----
    #pragma unroll
    for (int j = 0; j < 8; j++) {
        int id = tid + 256 * j;          // 0..2047
        int r  = id >> 5;                // 32 uint4-slots per 512B row
        int c  = (id & 31) * 8;
        int gr = row0 + r;
        uint4 v = make_uint4(0u, 0u, 0u, 0u);
        if (gr < M)
            v = *(const uint4*)(Xb + (size_t)gr * IN_DIM + c);
        *(uint4*)&As[r][c] = v;
    }
    __syncthreads();                     // the ONLY barrier

    floatx4 acc[4][8];
    #pragma unroll
    for (int i = 0; i < 4; i++)
        #pragma unroll
        for (int j = 0; j < 8; j++)
            acc[i][j] = (floatx4){0.f, 0.f, 0.f, 0.f};

    #pragma unroll 2
    for (int k0 = 0; k0 < IN_DIM; k0 += 32) {
        short8 af[4], bf[8];
        #pragma unroll
        for (int ni = 0; ni < 8; ni++)
            bf[ni] = *(const short8*)(WT +
                (size_t)(wx + ni * 16 + lrow) * IN_DIM + k0 + lk);
        #pragma unroll
        for (int mi = 0; mi < 4; mi++)
            af[mi] = *(const short8*)&As[mi * 16 + lrow][k0 + lk];

        #pragma unroll
        for (int mi = 0; mi < 4; mi++)
            #pragma unroll
            for (int ni = 0; ni < 8; ni++)
                acc[mi][ni] = __builtin_amdgcn_mfma_f32_16x16x32_bf16(
                    bf[ni], af[mi], acc[mi][ni], 0, 0, 0);
    }

    const int csub = (lane >> 4) * 4;
    const bool left = (wx < HC);         // wave-uniform: waves 0,1 -> xlb; 2,3 -> xrb
    const float*  bvec = left ? b_l : b_r;
    ushort*       obuf = left ? xlb : xrb;
    const int     cbase = left ? wx : wx - HC;
    #pragma unroll
    for (int mi = 0; mi < 4; mi++) {
        int grow = row0 + mi * 16 + lrow;
        if (grow < M) {
            #pragma unroll
            for (int ni = 0; ni < 8; ni++) {
                int lc = cbase + ni * 16 + csub;
                floatx4 v = acc[mi][ni];
                const float4 b = *(const float4*)(bvec + lc);
                union { ushort s[4]; uint2 u; } o;
                o.s[0] = f2bf(v[0] + b.x);
                o.s[1] = f2bf(v[1] + b.y);
                o.s[2] = f2bf(v[2] + b.z);
                o.s[3] = f2bf(v[3] + b.w);
                *(uint2*)(obuf + (size_t)grow * HC + lc) = o.u;
            }
        }
    }
}

// ---------------------------------------------------------------------------
// node_all v9 (UNCHANGED, measured <132 µs): v7 structure + att pre-scaled by
// log2(e) + raw v_exp_f32. Near its random-gather HBM floor (295 MB fetch at
// ~2.2 TB/s effective).
// ---------------------------------------------------------------------------
__global__ __launch_bounds__(192) void node_all(
    const ushort* __restrict__ xlb, const ushort* __restrict__ xrb,
    const int* __restrict__ cnt, const int* __restrict__ bucket,
    const float* __restrict__ att, const float* __restrict__ gw,
    const float* __restrict__ bias, float* __restrict__ out)
{
    __shared__ float lds[HOPS][CDIM];
    const int n    = blockIdx.x;
    const int k    = threadIdx.x >> 6;   // hop
    const int lane = threadIdx.x & 63;
    const int half = lane >> 5;          // which edge of the pair
    const int sub  = lane & 31;          // channel group: ch = sub*8 .. sub*8+7
    const unsigned laneoff = (unsigned)sub * 8;

    const int deg = min(cnt[k * N_NODES + n], CAP);
    const int* bk = bucket + ((size_t)k * N_NODES + n) * CAP;

    // xr channels for this lane (bf16 -> f32x2 pairs)
    uint4 rq = *(const uint4*)(xrb + (size_t)n * HC + laneoff);
    f32x2 rr[4] = { bf2x(rq.x), bf2x(rq.y), bf2x(rq.z), bf2x(rq.w) };

    // att pre-scaled by LOG2E: p is a log2-domain logit -> raw v_exp_f32
    const float4 a0 = ((const float4*)(att + (size_t)k * HC))[sub * 2 + 0];
    const float4 a1 = ((const float4*)(att + (size_t)k * HC))[sub * 2 + 1];
    f32x2 w2[4] = { {a0.x * LOG2E, a0.y * LOG2E}, {a0.z * LOG2E, a0.w * LOG2E},
                    {a1.x * LOG2E, a1.y * LOG2E}, {a1.z * LOG2E, a1.w * LOG2E} };

    float denom = 0.f;
    f32x2 acc2[4] = { {0.f,0.f}, {0.f,0.f}, {0.f,0.f}, {0.f,0.f} };

    if (deg > 0) {
        const int degm1 = deg - 1;
        int myS = (lane < deg) ? bk[lane] : 0;
        const int npair = (deg + 1) >> 1;

        int s0 = __shfl(myS, min(half, degm1));
        uint4 q = *(const uint4*)(xlb + (unsigned)s0 * HC + laneoff);

        for (int j = 0; j < npair; j++) {
            int sn = __shfl(myS, min(2 * (j + 1) + half, degm1));
            uint4 qn = *(const uint4*)(xlb + (unsigned)sn * HC + laneoff);

            f32x2 f0 = bf2x(q.x), f1 = bf2x(q.y);
            f32x2 f2 = bf2x(q.z), f3 = bf2x(q.w);

            f32x2 pp = w2[0] * lrelu2(f0 + rr[0]);
            pp = __builtin_elementwise_fma(w2[1], lrelu2(f1 + rr[1]), pp);
            pp = __builtin_elementwise_fma(w2[2], lrelu2(f2 + rr[2]), pp);
            pp = __builtin_elementwise_fma(w2[3], lrelu2(f3 + rr[3]), pp);
            float p = pp.x + pp.y;

            // per-head reduce: head = 8 consecutive lanes (within half)
            p += __shfl_xor(p, 1);
            p += __shfl_xor(p, 2);
            p += __shfl_xor(p, 4);

            bool valid = (2 * j + half) < deg;
            float ex = valid ? exp2_raw(p) : 0.f;
            denom += ex;
            f32x2 ex2 = { ex, ex };
            acc2[0] = __builtin_elementwise_fma(ex2, f0, acc2[0]);
            acc2[1] = __builtin_elementwise_fma(ex2, f1, acc2[1]);
            acc2[2] = __builtin_elementwise_fma(ex2, f2, acc2[2]);
            acc2[3] = __builtin_elementwise_fma(ex2, f3, acc2[3]);
            q = qn;
        }
    }

    // merge halves (xor-32): denom & acc are per-head after this.
    denom += __shfl_xor(denom, 32);
    const float inv = (denom > 0.f) ? 1.f / denom : 0.f;
    const float g   = gw[n * HOPS + k];
    const float* bb = bias + (size_t)k * CDIM + (size_t)(sub & 7) * 8;

    // per-head normalize FIRST (each lane still carries its own head),
    // THEN head mean across lanes {sub&7, +8, +16, +24} (xor-8, xor-16).
    #pragma unroll
    for (int i = 0; i < 4; i++) {
        acc2[i].x += __shfl_xor(acc2[i].x, 32);
        acc2[i].y += __shfl_xor(acc2[i].y, 32);
        acc2[i].x *= inv;
        acc2[i].y *= inv;
        acc2[i].x += __shfl_xor(acc2[i].x, 8);
        acc2[i].y += __shfl_xor(acc2[i].y, 8);
        acc2[i].x += __shfl_xor(acc2[i].x, 16);
        acc2[i].y += __shfl_xor(acc2[i].y, 16);
        if (lane < 8) {
            lds[k][lane * 8 + 2 * i]     = g * (acc2[i].x * 0.25f + bb[2 * i]);
            lds[k][lane * 8 + 2 * i + 1] = g * (acc2[i].y * 0.25f + bb[2 * i + 1]);
        }
    }
    __syncthreads();

    if (threadIdx.x < CDIM)
        out[(size_t)n * CDIM + threadIdx.x] =
            lds[0][threadIdx.x] + lds[1][threadIdx.x] + lds[2][threadIdx.x];
}

// ---------------------------------------------------------------------------
extern "C" void kernel_launch(void* const* d_in, const int* in_sizes, int n_in,
                              void* d_out, int out_size, void* d_ws, size_t ws_size,
                              hipStream_t stream)
{
    const float* x      = (const float*)d_in[0];
    const int*   ei0    = (const int*)d_in[1];
    const int*   ei1    = (const int*)d_in[2];
    const int*   ei2    = (const int*)d_in[3];
    const float* W_l    = (const float*)d_in[4];
    const float* b_l    = (const float*)d_in[5];
    const float* W_r    = (const float*)d_in[6];
    const float* b_r    = (const float*)d_in[7];
    const float* att    = (const float*)d_in[8];   // [3,4,64]
    const float* bias   = (const float*)d_in[9];   // [3,64]
    const float* W_gate = (const float*)d_in[10];  // [256,3]
    const float* b_gate = (const float*)d_in[11];  // [3]

    const size_t NHC = (size_t)N_NODES * HC;       // 12,800,000
    float* ws      = (float*)d_ws;
    float* gwbuf   = ws;                           // 150,000 floats
    int*   cnt     = (int*)(gwbuf + HOPS * N_NODES);         // 150,000 ints
    int*   bucket  = cnt + HOPS * N_NODES;         // 3*N*CAP = 6,000,000 ints
    ushort* xlb    = (ushort*)(bucket + (size_t)HOPS * N_NODES * CAP); // NHC bf16
    ushort* xrb    = xlb + NHC;                    // NHC bf16
    ushort* Xb     = xrb + NHC;                    // NHC bf16
    ushort* WT     = Xb + NHC;                     // 131,072 bf16

    // gate + pack_x | pack_w | zero-cnt (memset folded in; no extra launch)
    prep_a<<<NB_GATE + NB_PACKW + NB_ZERO, 256, 0, stream>>>(
        x, W_gate, b_gate, gwbuf, Xb, W_l, W_r, WT, cnt);

    // gemm v4 (A once + B from L2, barrier-free K-loop) + concurrent scatter
    gemm_scatter<<<FUSED_BLKS, 256, 0, stream>>>(
        Xb, WT, b_l, b_r, xlb, xrb, N_NODES,
        ei0, ei1, ei2, cnt, bucket);

    // fused logits + softmax + aggregate + head-mean + gate combine
    node_all<<<N_NODES, 192, 0, stream>>>(
        xlb, xrb, cnt, bucket, att, gwbuf, bias, (float*)d_out);
}